// Round 10
// baseline (235.286 us; speedup 1.0000x reference)
//
#include <hip/hip_runtime.h>
#include <math.h>

#define LL 512
#define EE 1024
#define HH 16
#define DD 64
#define NSX 16               // N*S
#define NT (NSX*LL)          // 8192 tokens
#define NSLE (NT*EE)         // 8388608
// q is pre-scaled by (1/sqrt(512)) * log2(e) so softmax uses native exp2
#define SCALE_Q 0.06375871f

typedef unsigned short u16;
typedef short bf16x8 __attribute__((ext_vector_type(8)));
typedef float f32x4 __attribute__((ext_vector_type(4)));

__device__ inline u16 f2bf(float f) {
  unsigned u = __float_as_uint(f);
  u += 0x7fff + ((u >> 16) & 1);          // RNE
  return (u16)(u >> 16);
}

// direct builtin calls only; ONLY gfx950-verified MFMA shapes (16x16x32)
#define FEXP2(x) __builtin_amdgcn_exp2f(x)
#define MFMA32(a, b, c) __builtin_amdgcn_mfma_f32_16x16x32_bf16((a), (b), (c), 0, 0, 0)

// ---------------- K0: convert weights fp32 -> bf16 ----------------
__global__ void __launch_bounds__(256) convw_kernel(
    const float* __restrict__ Wv, const float* __restrict__ Wk,
    const float* __restrict__ Wq, const float* __restrict__ Wo,
    u16* __restrict__ Wvb, u16* __restrict__ Wkb,
    u16* __restrict__ Wqb, u16* __restrict__ Wob) {
  int i = blockIdx.x * 256 + threadIdx.x;   // quad index
  const float* s; u16* d; int j;
  if (i < 262144) { s = Wo; d = Wob; j = i; }
  else {
    j = i - 262144;
    if (j < 1024)      { s = Wv; d = Wvb; }
    else if (j < 2048) { s = Wk; d = Wkb; j -= 1024; }
    else               { s = Wq; d = Wqb; j -= 2048; }
  }
  float4 f = ((const float4*)s)[j];
  ushort4 o; o.x = f2bf(f.x); o.y = f2bf(f.y); o.z = f2bf(f.z); o.w = f2bf(f.w);
  ((ushort4*)d)[j] = o;
}

// ---------------- K1: projections via MFMA, LDS-free, one wave = one head ----
// grid = mat(3) x ns(16) x ttile(32 of 16 tokens) x headgroup(4) = 6144 blocks.
// Per thread: 4 independent float4 loads (single latency exposure), 8 MFMA,
// store. No loop over heads -> compiler cannot serialize latency.
// v stored transposed vpT[ns][h][d][l]; k/q C-layout scatter.
__global__ void __launch_bounds__(256) proj_kernel(
    const float* __restrict__ vals, const float* __restrict__ keys,
    const float* __restrict__ qry,
    const u16* __restrict__ Wvb, const u16* __restrict__ Wkb,
    const u16* __restrict__ Wqb,
    u16* __restrict__ vpT, u16* __restrict__ kp, u16* __restrict__ qp) {
  const int b = blockIdx.x;
  const int hg = b & 3, tt = (b >> 2) & 31, ns = (b >> 7) & 15, mat = b >> 11;
  const int tid = threadIdx.x;
  const int wid = tid >> 6, lane = tid & 63, quad = lane >> 4, l16 = lane & 15;
  const int h = hg*4 + wid;
  const float* src = (mat == 0 ? vals : mat == 1 ? keys : qry);
  const u16*   W   = (mat == 0 ? Wvb  : mat == 1 ? Wkb  : Wqb);
  const int t0 = ns*LL + tt*16;
  // ---- X loads (HBM): 4 independent float4, issued together ----
  const float* xrow = src + (size_t)(t0 + l16)*EE + h*DD;
  float4 x0 = *(const float4*)&xrow[quad*8];
  float4 x1 = *(const float4*)&xrow[quad*8 + 4];
  float4 x2 = *(const float4*)&xrow[32 + quad*8];
  float4 x3 = *(const float4*)&xrow[32 + quad*8 + 4];
  // ---- W fragments (L2-resident, 8 KB/mat) ----
  bf16x8 wf[4][2];
  #pragma unroll
  for (int nt = 0; nt < 4; ++nt) {
    wf[nt][0] = *(const bf16x8*)&W[(nt*16 + l16)*DD + quad*8];
    wf[nt][1] = *(const bf16x8*)&W[(nt*16 + l16)*DD + 32 + quad*8];
  }
  // ---- convert A fragments ----
  bf16x8 af0, af1;
  af0[0] = (short)f2bf(x0.x); af0[1] = (short)f2bf(x0.y);
  af0[2] = (short)f2bf(x0.z); af0[3] = (short)f2bf(x0.w);
  af0[4] = (short)f2bf(x1.x); af0[5] = (short)f2bf(x1.y);
  af0[6] = (short)f2bf(x1.z); af0[7] = (short)f2bf(x1.w);
  af1[0] = (short)f2bf(x2.x); af1[1] = (short)f2bf(x2.y);
  af1[2] = (short)f2bf(x2.z); af1[3] = (short)f2bf(x2.w);
  af1[4] = (short)f2bf(x3.x); af1[5] = (short)f2bf(x3.y);
  af1[6] = (short)f2bf(x3.z); af1[7] = (short)f2bf(x3.w);
  f32x4 z = {0.f, 0.f, 0.f, 0.f};
  f32x4 acc[4];
  #pragma unroll
  for (int nt = 0; nt < 4; ++nt) {
    acc[nt] = MFMA32(af0, wf[nt][0], z);
    acc[nt] = MFMA32(af1, wf[nt][1], acc[nt]);
  }
  if (mat == 0) {
    // transposed store: rows d = nt*16+l16, 4 consecutive tokens as ushort4
    #pragma unroll
    for (int nt = 0; nt < 4; ++nt) {
      ushort4 o;
      o.x = f2bf(acc[nt][0]); o.y = f2bf(acc[nt][1]);
      o.z = f2bf(acc[nt][2]); o.w = f2bf(acc[nt][3]);
      size_t idx = ((size_t)((ns*HH + h)*DD + nt*16 + l16))*LL + tt*16 + quad*4;
      *(ushort4*)&vpT[idx] = o;
    }
  } else {
    u16* dst = (mat == 1 ? kp : qp);
    const float sc = (mat == 2) ? SCALE_Q : 1.f;
    // C-layout scatter: row token = t0+quad*4+r, col = h*64+nt*16+l16
    #pragma unroll
    for (int nt = 0; nt < 4; ++nt)
      #pragma unroll
      for (int r = 0; r < 4; ++r)
        dst[(size_t)(t0 + quad*4 + r)*EE + h*DD + nt*16 + l16] =
            f2bf(acc[nt][r] * sc);
  }
}

// ---------------- K2: fused column-softmax + attention-out ----------------
// one block per (ns,h): 256 blocks x 1024 threads. K resident in LDS; V chunk
// double-buffered; P via per-wave LDS transpose; MFMA32 only.
// softmax is over the QUERY axis: colsum_l = sum_q mask_q * exp2(e_ql).
__global__ void __launch_bounds__(1024, 4) attn_kernel(
    const u16* __restrict__ qp, const u16* __restrict__ kp,
    const u16* __restrict__ vpT, const int* __restrict__ mask,
    u16* __restrict__ oat) {
  const int b = blockIdx.x;
  const int h = b & 15, ns = b >> 4;
  const int tid = threadIdx.x;
  const int wid = tid >> 6, lane = tid & 63, quad = lane >> 4, l16 = lane & 15;
  __shared__ u16 Ks[LL][72];        // K[l][d]      73728 B
  __shared__ u16 Vt[2][DD][72];     // V^T[d][l64]  18432 B
  __shared__ u16 pt[16][32][40];    // per-wave P   40960 B (phase A: psum f32[16][512])
  __shared__ float csum[LL];        //               2048 B   => 135168 B total
  float* psum = (float*)pt;
  // ---- stage K ----
  const size_t kgbase = ((size_t)(ns*LL))*EE + h*DD;
  for (int i = tid; i < 4096; i += 1024) {          // 512 rows x 8 segs of 16B
    int row = i >> 3, seg = (i & 7) * 8;
    *(bf16x8*)&Ks[row][seg] = *(const bf16x8*)&kp[kgbase + (size_t)row*EE + seg];
  }
  // ---- persistent Q fragments (wave owns 32 q rows) + masks ----
  const int q0 = wid*32;
  bf16x8 qf[2][2];
  float maf[2][4];
  #pragma unroll
  for (int qt = 0; qt < 2; ++qt) {
    const u16* qrow = qp + ((size_t)(ns*LL + q0 + qt*16 + l16))*EE + h*DD;
    qf[qt][0] = *(const bf16x8*)&qrow[quad*8];
    qf[qt][1] = *(const bf16x8*)&qrow[32 + quad*8];
    #pragma unroll
    for (int r = 0; r < 4; ++r)
      maf[qt][r] = mask[ns*LL + q0 + qt*16 + quad*4 + r] ? 1.f : 0.f;
  }
  f32x4 z = {0.f, 0.f, 0.f, 0.f};
  __syncthreads();
  // ---- phase A: column partial sums -> psum[wid][l], then block reduce ----
  for (int lt = 0; lt < 32; ++lt) {
    bf16x8 kf0 = *(const bf16x8*)&Ks[lt*16 + l16][quad*8];
    bf16x8 kf1 = *(const bf16x8*)&Ks[lt*16 + l16][32 + quad*8];
    float part = 0.f;
    #pragma unroll
    for (int qt = 0; qt < 2; ++qt) {
      f32x4 e = MFMA32(qf[qt][0], kf0, z);
      e = MFMA32(qf[qt][1], kf1, e);
      #pragma unroll
      for (int r = 0; r < 4; ++r)
        part += maf[qt][r] * FEXP2(e[r]);     // e row = q(quad*4+r), col = l(l16)
    }
    part += __shfl_xor(part, 16);             // combine 4 quads (same l16)
    part += __shfl_xor(part, 32);
    if (quad == 0) psum[wid*512 + lt*16 + l16] = part;
  }
  __syncthreads();
  if (tid < LL) {
    float s = 0.f;
    #pragma unroll
    for (int w = 0; w < 16; ++w) s += psum[w*512 + tid];
    csum[tid] = (s > 0.f) ? 1.f/s : 0.f;
  }
  __syncthreads();
  // ---- phase B: E recompute -> P (LDS transpose) -> PV, V chunks of 64 l ----
  f32x4 acc[4][2] = {{z,z},{z,z},{z,z},{z,z}};   // [dtile][qt]
  const size_t vgbase = ((size_t)((ns*HH + h)*DD))*LL;
  for (int lc = 0; lc < 8; ++lc) {               // 8 chunks of 64 l
    if (tid < 512) {                             // stage V^T[d][lc*64..+63]
      int row = tid >> 3, seg = (tid & 7) * 8;
      *(bf16x8*)&Vt[lc & 1][row][seg] =
          *(const bf16x8*)&vpT[vgbase + (size_t)row*LL + lc*64 + seg];
    }
    __syncthreads();                             // one barrier per chunk (dbuf)
    // E + P for 64 l in 4 sub-tiles of 16
    #pragma unroll
    for (int lt2 = 0; lt2 < 4; ++lt2) {
      const int lrow = lc*64 + lt2*16 + l16;
      bf16x8 kf0 = *(const bf16x8*)&Ks[lrow][quad*8];
      bf16x8 kf1 = *(const bf16x8*)&Ks[lrow][32 + quad*8];
      const float csv = csum[lrow];
      #pragma unroll
      for (int qt = 0; qt < 2; ++qt) {
        f32x4 e = MFMA32(qf[qt][0], kf0, z);
        e = MFMA32(qf[qt][1], kf1, e);
        #pragma unroll
        for (int r = 0; r < 4; ++r)
          pt[wid][qt*16 + quad*4 + r][lt2 & 1 ? 16 + l16 : l16] =
              f2bf(maf[qt][r] * csv * FEXP2(e[r]));
        // PV for the 32-l half once both sub-tiles of it are in pt
        if (lt2 & 1) {
          bf16x8 pa = *(const bf16x8*)&pt[wid][qt*16 + l16][quad*8];
          #pragma unroll
          for (int dt = 0; dt < 4; ++dt) {
            bf16x8 vb = *(const bf16x8*)&Vt[lc & 1][dt*16 + l16]
                                        [(lt2 >> 1)*32 + quad*8];
            acc[dt][qt] = MFMA32(pa, vb, acc[dt][qt]);
          }
        }
      }
    }
  }
  // ---- write out[q][d]: D row = q(quad*4+r), col = d(l16) ----
  #pragma unroll
  for (int qt = 0; qt < 2; ++qt)
    #pragma unroll
    for (int dt = 0; dt < 4; ++dt)
      #pragma unroll
      for (int r = 0; r < 4; ++r)
        oat[((size_t)(ns*LL + q0 + qt*16 + quad*4 + r))*EE + h*DD + dt*16 + l16] =
            f2bf(acc[dt][qt][r]);
}

// ---------------- K4: Y = oat @ Wo^T + bo, LDS-tiled MFMA GEMM ----------------
// 128x128 tile, BK=64, 4 waves each computing a 64x64 quadrant.
__global__ void __launch_bounds__(256) out_gemm_kernel(
    const u16* __restrict__ A, const u16* __restrict__ Wob,
    const float* __restrict__ bo, float* __restrict__ Y) {
  __shared__ u16 As[128][72];   // [m][k]  18432 B
  __shared__ u16 Bs[128][72];   // [n][k]  18432 B
  const int b = blockIdx.x;     // 64 mtiles x 8 ntiles
  const int nb = b & 7, mb = b >> 3;
  const int m0 = mb*128, n0 = nb*128;
  const int tid = threadIdx.x;
  const int wid = tid >> 6, lane = tid & 63, quad = lane >> 4, l16 = lane & 15;
  const int wm = (wid >> 1)*64, wn = (wid & 1)*64;   // wave quadrant
  f32x4 z = {0.f, 0.f, 0.f, 0.f};
  f32x4 acc[4][4];
  #pragma unroll
  for (int i = 0; i < 4; ++i)
    #pragma unroll
    for (int j = 0; j < 4; ++j) acc[i][j] = z;
  for (int k0 = 0; k0 < EE; k0 += 64) {
    __syncthreads();
    #pragma unroll
    for (int it = 0; it < 4; ++it) {      // stage 128 rows x 64 k each
      int idx = it*256 + tid;
      int row = idx >> 3, seg = (idx & 7) * 8;
      *(bf16x8*)&As[row][seg] = *(const bf16x8*)&A  [(size_t)(m0 + row)*EE + k0 + seg];
      *(bf16x8*)&Bs[row][seg] = *(const bf16x8*)&Wob[(size_t)(n0 + row)*EE + k0 + seg];
    }
    __syncthreads();
    #pragma unroll
    for (int kk = 0; kk < 2; ++kk) {
      bf16x8 af[4], bfr[4];
      #pragma unroll
      for (int i = 0; i < 4; ++i)
        af[i] = *(const bf16x8*)&As[wm + i*16 + l16][kk*32 + quad*8];
      #pragma unroll
      for (int j = 0; j < 4; ++j)
        bfr[j] = *(const bf16x8*)&Bs[wn + j*16 + l16][kk*32 + quad*8];
      #pragma unroll
      for (int i = 0; i < 4; ++i)
        #pragma unroll
        for (int j = 0; j < 4; ++j)
          acc[i][j] = MFMA32(af[i], bfr[j], acc[i][j]);
    }
  }
  #pragma unroll
  for (int i = 0; i < 4; ++i)
    #pragma unroll
    for (int j = 0; j < 4; ++j) {
      int col = n0 + wn + j*16 + l16;
      float bias = bo[col];
      #pragma unroll
      for (int r = 0; r < 4; ++r)
        Y[(size_t)(m0 + wm + i*16 + quad*4 + r)*EE + col] = acc[i][j][r] + bias;
    }
}

extern "C" void kernel_launch(void* const* d_in, const int* in_sizes, int n_in,
                              void* d_out, int out_size, void* d_ws, size_t ws_size,
                              hipStream_t stream) {
  const float* values = (const float*)d_in[0];
  const float* keysp  = (const float*)d_in[1];
  const float* query  = (const float*)d_in[2];
  const int*   mask   = (const int*)d_in[3];
  const float* Wv = (const float*)d_in[4];
  const float* Wk = (const float*)d_in[5];
  const float* Wq = (const float*)d_in[6];
  const float* Wo = (const float*)d_in[7];
  const float* bo = (const float*)d_in[8];
  float* Y = (float*)d_out;

  u16* qp  = (u16*)d_ws;
  u16* kp  = qp + NSLE;
  u16* vpT = kp + NSLE;
  u16* oat = vpT + NSLE;
  u16* Wob = oat + NSLE;
  u16* Wvb = Wob + EE*EE;
  u16* Wkb = Wvb + DD*DD;
  u16* Wqb = Wkb + DD*DD;

  convw_kernel<<<1036, 256, 0, stream>>>(Wv, Wk, Wq, Wo, Wvb, Wkb, Wqb, Wob);
  proj_kernel<<<3*NSX*32*4, 256, 0, stream>>>(values, keysp, query,
                                              Wvb, Wkb, Wqb, vpT, kp, qp);
  attn_kernel<<<NSX*HH, 1024, 0, stream>>>(qp, kp, vpT, mask, oat);
  out_gemm_kernel<<<(NT/128)*(EE/128), 256, 0, stream>>>(oat, Wob, bo, Y);
}

// Round 11
// 226.055 us; speedup vs baseline: 1.0408x; 1.0408x over previous
//
#include <hip/hip_runtime.h>
#include <math.h>

#define LL 512
#define EE 1024
#define HH 16
#define DD 64
#define NSX 16               // N*S
#define NT (NSX*LL)          // 8192 tokens
#define NSLE (NT*EE)         // 8388608
// q is pre-scaled by (1/sqrt(512)) * log2(e) so softmax uses native exp2
#define SCALE_Q 0.06375871f

typedef unsigned short u16;
typedef short bf16x8 __attribute__((ext_vector_type(8)));
typedef float f32x4 __attribute__((ext_vector_type(4)));

__device__ inline u16 f2bf(float f) {
  unsigned u = __float_as_uint(f);
  u += 0x7fff + ((u >> 16) & 1);          // RNE
  return (u16)(u >> 16);
}

// direct builtin calls only; ONLY gfx950-verified MFMA shapes (16x16x32)
#define FEXP2(x) __builtin_amdgcn_exp2f(x)
#define MFMA32(a, b, c) __builtin_amdgcn_mfma_f32_16x16x32_bf16((a), (b), (c), 0, 0, 0)

// ---------------- K0: convert weights fp32 -> bf16 ----------------
__global__ void __launch_bounds__(256) convw_kernel(
    const float* __restrict__ Wv, const float* __restrict__ Wk,
    const float* __restrict__ Wq, const float* __restrict__ Wo,
    u16* __restrict__ Wvb, u16* __restrict__ Wkb,
    u16* __restrict__ Wqb, u16* __restrict__ Wob) {
  int i = blockIdx.x * 256 + threadIdx.x;   // quad index
  const float* s; u16* d; int j;
  if (i < 262144) { s = Wo; d = Wob; j = i; }
  else {
    j = i - 262144;
    if (j < 1024)      { s = Wv; d = Wvb; }
    else if (j < 2048) { s = Wk; d = Wkb; j -= 1024; }
    else               { s = Wq; d = Wqb; j -= 2048; }
  }
  float4 f = ((const float4*)s)[j];
  ushort4 o; o.x = f2bf(f.x); o.y = f2bf(f.y); o.z = f2bf(f.z); o.w = f2bf(f.w);
  ((ushort4*)d)[j] = o;
}

// ---------------- K1: projections via MFMA, LDS-free, 4-deep pipelined -------
// grid = mat(3) x ns(16) x hg(4) x tt0(8) = 1536 blocks; wave = one head; each
// wave processes 4 token-tiles (tt = tt0 + 8j) with the NEXT tile's X loads
// issued before the current tile's convert/MFMA/store (latency overlap).
// v stored transposed vpT[ns][h][d][l]; k/q C-layout scatter.
__global__ void __launch_bounds__(256) proj_kernel(
    const float* __restrict__ vals, const float* __restrict__ keys,
    const float* __restrict__ qry,
    const u16* __restrict__ Wvb, const u16* __restrict__ Wkb,
    const u16* __restrict__ Wqb,
    u16* __restrict__ vpT, u16* __restrict__ kp, u16* __restrict__ qp) {
  const int b = blockIdx.x;
  const int tt0 = b & 7, hg = (b >> 3) & 3, ns = (b >> 5) & 15, mat = b >> 9;
  const int tid = threadIdx.x;
  const int wid = tid >> 6, lane = tid & 63, quad = lane >> 4, l16 = lane & 15;
  const int h = hg*4 + wid;
  const float* src = (mat == 0 ? vals : mat == 1 ? keys : qry);
  const u16*   W   = (mat == 0 ? Wvb  : mat == 1 ? Wkb  : Wqb);
  u16* dst = (mat == 1 ? kp : qp);
  const float sc = (mat == 2) ? SCALE_Q : 1.f;
  // ---- W fragments: loaded once, register-resident across all 4 tiles ----
  bf16x8 wf[4][2];
  #pragma unroll
  for (int nt = 0; nt < 4; ++nt) {
    wf[nt][0] = *(const bf16x8*)&W[(nt*16 + l16)*DD + quad*8];
    wf[nt][1] = *(const bf16x8*)&W[(nt*16 + l16)*DD + 32 + quad*8];
  }
  f32x4 z = {0.f, 0.f, 0.f, 0.f};
  // ---- prologue: loads for tile j=0 ----
  const float* xrow0 = src + (size_t)(ns*LL + tt0*16 + l16)*EE + h*DD;
  float4 x0 = *(const float4*)&xrow0[quad*8];
  float4 x1 = *(const float4*)&xrow0[quad*8 + 4];
  float4 x2 = *(const float4*)&xrow0[32 + quad*8];
  float4 x3 = *(const float4*)&xrow0[32 + quad*8 + 4];
  #pragma unroll
  for (int j = 0; j < 4; ++j) {
    const int tt = tt0 + 8*j;
    const int t0 = ns*LL + tt*16;
    // ---- issue NEXT tile's loads before touching this tile's data ----
    float4 n0, n1, n2, n3;
    if (j < 3) {
      const float* xrown = src + (size_t)(t0 + 8*16 + l16)*EE + h*DD;
      n0 = *(const float4*)&xrown[quad*8];
      n1 = *(const float4*)&xrown[quad*8 + 4];
      n2 = *(const float4*)&xrown[32 + quad*8];
      n3 = *(const float4*)&xrown[32 + quad*8 + 4];
    }
    // ---- convert current tile ----
    bf16x8 af0, af1;
    af0[0] = (short)f2bf(x0.x); af0[1] = (short)f2bf(x0.y);
    af0[2] = (short)f2bf(x0.z); af0[3] = (short)f2bf(x0.w);
    af0[4] = (short)f2bf(x1.x); af0[5] = (short)f2bf(x1.y);
    af0[6] = (short)f2bf(x1.z); af0[7] = (short)f2bf(x1.w);
    af1[0] = (short)f2bf(x2.x); af1[1] = (short)f2bf(x2.y);
    af1[2] = (short)f2bf(x2.z); af1[3] = (short)f2bf(x2.w);
    af1[4] = (short)f2bf(x3.x); af1[5] = (short)f2bf(x3.y);
    af1[6] = (short)f2bf(x3.z); af1[7] = (short)f2bf(x3.w);
    f32x4 acc[4];
    #pragma unroll
    for (int nt = 0; nt < 4; ++nt) {
      acc[nt] = MFMA32(af0, wf[nt][0], z);
      acc[nt] = MFMA32(af1, wf[nt][1], acc[nt]);
    }
    if (mat == 0) {
      // transposed store: rows d = nt*16+l16, 4 consecutive tokens as ushort4
      #pragma unroll
      for (int nt = 0; nt < 4; ++nt) {
        ushort4 o;
        o.x = f2bf(acc[nt][0]); o.y = f2bf(acc[nt][1]);
        o.z = f2bf(acc[nt][2]); o.w = f2bf(acc[nt][3]);
        size_t idx = ((size_t)((ns*HH + h)*DD + nt*16 + l16))*LL + tt*16 + quad*4;
        *(ushort4*)&vpT[idx] = o;
      }
    } else {
      // C-layout scatter: row token = t0+quad*4+r, col = h*64+nt*16+l16
      #pragma unroll
      for (int nt = 0; nt < 4; ++nt)
        #pragma unroll
        for (int r = 0; r < 4; ++r)
          dst[(size_t)(t0 + quad*4 + r)*EE + h*DD + nt*16 + l16] =
              f2bf(acc[nt][r] * sc);
    }
    x0 = n0; x1 = n1; x2 = n2; x3 = n3;
  }
}

// ---------------- K2: fused column-softmax + attention-out ----------------
// one block per (ns,h): 256 blocks x 1024 threads. K resident in LDS; V chunk
// double-buffered; P via per-wave LDS transpose; MFMA32 only.
// softmax is over the QUERY axis: colsum_l = sum_q mask_q * exp2(e_ql).
__global__ void __launch_bounds__(1024, 4) attn_kernel(
    const u16* __restrict__ qp, const u16* __restrict__ kp,
    const u16* __restrict__ vpT, const int* __restrict__ mask,
    u16* __restrict__ oat) {
  const int b = blockIdx.x;
  const int h = b & 15, ns = b >> 4;
  const int tid = threadIdx.x;
  const int wid = tid >> 6, lane = tid & 63, quad = lane >> 4, l16 = lane & 15;
  __shared__ u16 Ks[LL][72];        // K[l][d]      73728 B
  __shared__ u16 Vt[2][DD][72];     // V^T[d][l64]  18432 B
  __shared__ u16 pt[16][32][40];    // per-wave P   40960 B (phase A: psum f32[16][512])
  __shared__ float csum[LL];        //               2048 B   => 135168 B total
  float* psum = (float*)pt;
  // ---- stage K ----
  const size_t kgbase = ((size_t)(ns*LL))*EE + h*DD;
  for (int i = tid; i < 4096; i += 1024) {          // 512 rows x 8 segs of 16B
    int row = i >> 3, seg = (i & 7) * 8;
    *(bf16x8*)&Ks[row][seg] = *(const bf16x8*)&kp[kgbase + (size_t)row*EE + seg];
  }
  // ---- persistent Q fragments (wave owns 32 q rows) + masks ----
  const int q0 = wid*32;
  bf16x8 qf[2][2];
  float maf[2][4];
  #pragma unroll
  for (int qt = 0; qt < 2; ++qt) {
    const u16* qrow = qp + ((size_t)(ns*LL + q0 + qt*16 + l16))*EE + h*DD;
    qf[qt][0] = *(const bf16x8*)&qrow[quad*8];
    qf[qt][1] = *(const bf16x8*)&qrow[32 + quad*8];
    #pragma unroll
    for (int r = 0; r < 4; ++r)
      maf[qt][r] = mask[ns*LL + q0 + qt*16 + quad*4 + r] ? 1.f : 0.f;
  }
  f32x4 z = {0.f, 0.f, 0.f, 0.f};
  __syncthreads();
  // ---- phase A: column partial sums -> psum[wid][l], then block reduce ----
  for (int lt = 0; lt < 32; ++lt) {
    bf16x8 kf0 = *(const bf16x8*)&Ks[lt*16 + l16][quad*8];
    bf16x8 kf1 = *(const bf16x8*)&Ks[lt*16 + l16][32 + quad*8];
    float part = 0.f;
    #pragma unroll
    for (int qt = 0; qt < 2; ++qt) {
      f32x4 e = MFMA32(qf[qt][0], kf0, z);
      e = MFMA32(qf[qt][1], kf1, e);
      #pragma unroll
      for (int r = 0; r < 4; ++r)
        part += maf[qt][r] * FEXP2(e[r]);     // e row = q(quad*4+r), col = l(l16)
    }
    part += __shfl_xor(part, 16);             // combine 4 quads (same l16)
    part += __shfl_xor(part, 32);
    if (quad == 0) psum[wid*512 + lt*16 + l16] = part;
  }
  __syncthreads();
  if (tid < LL) {
    float s = 0.f;
    #pragma unroll
    for (int w = 0; w < 16; ++w) s += psum[w*512 + tid];
    csum[tid] = (s > 0.f) ? 1.f/s : 0.f;
  }
  __syncthreads();
  // ---- phase B: E recompute -> P (LDS transpose) -> PV, V chunks of 64 l ----
  f32x4 acc[4][2] = {{z,z},{z,z},{z,z},{z,z}};   // [dtile][qt]
  const size_t vgbase = ((size_t)((ns*HH + h)*DD))*LL;
  for (int lc = 0; lc < 8; ++lc) {               // 8 chunks of 64 l
    if (tid < 512) {                             // stage V^T[d][lc*64..+63]
      int row = tid >> 3, seg = (tid & 7) * 8;
      *(bf16x8*)&Vt[lc & 1][row][seg] =
          *(const bf16x8*)&vpT[vgbase + (size_t)row*LL + lc*64 + seg];
    }
    __syncthreads();                             // one barrier per chunk (dbuf)
    // E + P for 64 l in 4 sub-tiles of 16
    #pragma unroll
    for (int lt2 = 0; lt2 < 4; ++lt2) {
      const int lrow = lc*64 + lt2*16 + l16;
      bf16x8 kf0 = *(const bf16x8*)&Ks[lrow][quad*8];
      bf16x8 kf1 = *(const bf16x8*)&Ks[lrow][32 + quad*8];
      const float csv = csum[lrow];
      #pragma unroll
      for (int qt = 0; qt < 2; ++qt) {
        f32x4 e = MFMA32(qf[qt][0], kf0, z);
        e = MFMA32(qf[qt][1], kf1, e);
        #pragma unroll
        for (int r = 0; r < 4; ++r)
          pt[wid][qt*16 + quad*4 + r][lt2 & 1 ? 16 + l16 : l16] =
              f2bf(maf[qt][r] * csv * FEXP2(e[r]));
        // PV for the 32-l half once both sub-tiles of it are in pt
        if (lt2 & 1) {
          bf16x8 pa = *(const bf16x8*)&pt[wid][qt*16 + l16][quad*8];
          #pragma unroll
          for (int dt = 0; dt < 4; ++dt) {
            bf16x8 vb = *(const bf16x8*)&Vt[lc & 1][dt*16 + l16]
                                        [(lt2 >> 1)*32 + quad*8];
            acc[dt][qt] = MFMA32(pa, vb, acc[dt][qt]);
          }
        }
      }
    }
  }
  // ---- write out[q][d]: D row = q(quad*4+r), col = d(l16) ----
  #pragma unroll
  for (int qt = 0; qt < 2; ++qt)
    #pragma unroll
    for (int dt = 0; dt < 4; ++dt)
      #pragma unroll
      for (int r = 0; r < 4; ++r)
        oat[((size_t)(ns*LL + q0 + qt*16 + quad*4 + r))*EE + h*DD + dt*16 + l16] =
            f2bf(acc[dt][qt][r]);
}

// ---------------- K4: Y = oat @ Wo^T + bo, LDS-tiled MFMA GEMM ----------------
// 128x128 tile, BK=64, 4 waves each computing a 64x64 quadrant.
__global__ void __launch_bounds__(256) out_gemm_kernel(
    const u16* __restrict__ A, const u16* __restrict__ Wob,
    const float* __restrict__ bo, float* __restrict__ Y) {
  __shared__ u16 As[128][72];   // [m][k]  18432 B
  __shared__ u16 Bs[128][72];   // [n][k]  18432 B
  const int b = blockIdx.x;     // 64 mtiles x 8 ntiles
  const int nb = b & 7, mb = b >> 3;
  const int m0 = mb*128, n0 = nb*128;
  const int tid = threadIdx.x;
  const int wid = tid >> 6, lane = tid & 63, quad = lane >> 4, l16 = lane & 15;
  const int wm = (wid >> 1)*64, wn = (wid & 1)*64;   // wave quadrant
  f32x4 z = {0.f, 0.f, 0.f, 0.f};
  f32x4 acc[4][4];
  #pragma unroll
  for (int i = 0; i < 4; ++i)
    #pragma unroll
    for (int j = 0; j < 4; ++j) acc[i][j] = z;
  for (int k0 = 0; k0 < EE; k0 += 64) {
    __syncthreads();
    #pragma unroll
    for (int it = 0; it < 4; ++it) {      // stage 128 rows x 64 k each
      int idx = it*256 + tid;
      int row = idx >> 3, seg = (idx & 7) * 8;
      *(bf16x8*)&As[row][seg] = *(const bf16x8*)&A  [(size_t)(m0 + row)*EE + k0 + seg];
      *(bf16x8*)&Bs[row][seg] = *(const bf16x8*)&Wob[(size_t)(n0 + row)*EE + k0 + seg];
    }
    __syncthreads();
    #pragma unroll
    for (int kk = 0; kk < 2; ++kk) {
      bf16x8 af[4], bfr[4];
      #pragma unroll
      for (int i = 0; i < 4; ++i)
        af[i] = *(const bf16x8*)&As[wm + i*16 + l16][kk*32 + quad*8];
      #pragma unroll
      for (int j = 0; j < 4; ++j)
        bfr[j] = *(const bf16x8*)&Bs[wn + j*16 + l16][kk*32 + quad*8];
      #pragma unroll
      for (int i = 0; i < 4; ++i)
        #pragma unroll
        for (int j = 0; j < 4; ++j)
          acc[i][j] = MFMA32(af[i], bfr[j], acc[i][j]);
    }
  }
  #pragma unroll
  for (int i = 0; i < 4; ++i)
    #pragma unroll
    for (int j = 0; j < 4; ++j) {
      int col = n0 + wn + j*16 + l16;
      float bias = bo[col];
      #pragma unroll
      for (int r = 0; r < 4; ++r)
        Y[(size_t)(m0 + wm + i*16 + quad*4 + r)*EE + col] = acc[i][j][r] + bias;
    }
}

extern "C" void kernel_launch(void* const* d_in, const int* in_sizes, int n_in,
                              void* d_out, int out_size, void* d_ws, size_t ws_size,
                              hipStream_t stream) {
  const float* values = (const float*)d_in[0];
  const float* keysp  = (const float*)d_in[1];
  const float* query  = (const float*)d_in[2];
  const int*   mask   = (const int*)d_in[3];
  const float* Wv = (const float*)d_in[4];
  const float* Wk = (const float*)d_in[5];
  const float* Wq = (const float*)d_in[6];
  const float* Wo = (const float*)d_in[7];
  const float* bo = (const float*)d_in[8];
  float* Y = (float*)d_out;

  u16* qp  = (u16*)d_ws;
  u16* kp  = qp + NSLE;
  u16* vpT = kp + NSLE;
  u16* oat = vpT + NSLE;
  u16* Wob = oat + NSLE;
  u16* Wvb = Wob + EE*EE;
  u16* Wkb = Wvb + DD*DD;
  u16* Wqb = Wkb + DD*DD;

  convw_kernel<<<1036, 256, 0, stream>>>(Wv, Wk, Wq, Wo, Wvb, Wkb, Wqb, Wob);
  proj_kernel<<<3*NSX*4*8, 256, 0, stream>>>(values, keysp, query,
                                             Wvb, Wkb, Wqb, vpT, kp, qp);
  attn_kernel<<<NSX*HH, 1024, 0, stream>>>(qp, kp, vpT, mask, oat);
  out_gemm_kernel<<<(NT/128)*(EE/128), 256, 0, stream>>>(oat, Wob, bo, Y);
}